// Round 1
// baseline (643.559 us; speedup 1.0000x reference)
//
#include <hip/hip_runtime.h>
#include <math.h>

#define NTOK 87040
#define DIM 512
#define NH 8
#define NROWS 1024   // B*Nq = 2*512

// ---------------------------------------------------------------------------
// Kernel 1: Q = query @ Wq + bq      (4 rows per block)
// ---------------------------------------------------------------------------
__global__ __launch_bounds__(256)
void k_qproj(const float* __restrict__ X, const float* __restrict__ W,
             const float* __restrict__ bias, float* __restrict__ Y) {
    __shared__ float xr[4][DIM];
    const int r0 = blockIdx.x * 4;
    const int t  = threadIdx.x;
    for (int i = t; i < 4 * DIM; i += 256)
        ((float*)xr)[i] = X[(size_t)r0 * DIM + i];
    __syncthreads();
    for (int rep = 0; rep < 2; ++rep) {
        const int c = t + rep * 256;
        float a[4];
        #pragma unroll
        for (int rr = 0; rr < 4; ++rr) a[rr] = bias[c];
        for (int d = 0; d < DIM; ++d) {
            const float wv = W[d * DIM + c];
            #pragma unroll
            for (int rr = 0; rr < 4; ++rr) a[rr] = fmaf(xr[rr][d], wv, a[rr]);
        }
        #pragma unroll
        for (int rr = 0; rr < 4; ++rr) Y[(size_t)(r0 + rr) * DIM + c] = a[rr];
    }
}

// ---------------------------------------------------------------------------
// Kernel 2: qtilde[r,h,d] = sum_j Q[r,h*64+j] * Wk[d, h*64+j]
//           qb[r,h]       = sum_j Q[r,h*64+j] * bk[h*64+j]
// ---------------------------------------------------------------------------
__global__ __launch_bounds__(256)
void k_qtilde(const float* __restrict__ Q, const float* __restrict__ Wk,
              const float* __restrict__ bk, float* __restrict__ qtilde,
              float* __restrict__ qb) {
    __shared__ float qr[4][DIM];
    const int r0 = blockIdx.x * 4;
    const int t  = threadIdx.x;
    for (int i = t; i < 4 * DIM; i += 256)
        ((float*)qr)[i] = Q[(size_t)r0 * DIM + i];
    __syncthreads();
    if (t < 32) {
        const int rr = t >> 3, h = t & 7;
        float a = 0.f;
        for (int j = 0; j < 64; ++j)
            a = fmaf(qr[rr][h * 64 + j], bk[h * 64 + j], a);
        qb[(r0 + rr) * NH + h] = a;
    }
    for (int chunk = 0; chunk < 16; ++chunk) {
        const int c = chunk * 256 + t;       // 0..4095 -> (h,d)
        const int h = c >> 9, d = c & 511;
        float a[4];
        #pragma unroll
        for (int rr = 0; rr < 4; ++rr) a[rr] = 0.f;
        const float* wkp = Wk + (size_t)d * DIM + h * 64;
        for (int j = 0; j < 64; ++j) {
            const float wv = wkp[j];
            #pragma unroll
            for (int rr = 0; rr < 4; ++rr) a[rr] = fmaf(qr[rr][h * 64 + j], wv, a[rr]);
        }
        #pragma unroll
        for (int rr = 0; rr < 4; ++rr)
            qtilde[(size_t)(r0 + rr) * (NH * DIM) + c] = a[rr];
    }
}

// ---------------------------------------------------------------------------
// Kernel 3: flash attention over 512 window keys; accumulates weighted RAW
// token sum per head into tsum[r][h][512].
// One block (8 waves) per query row. Wave w handles keys [w*64, w*64+64);
// level id = w>>1 (wave-uniform). Lanes spread over the 512 dims (8 each).
// ---------------------------------------------------------------------------
__global__ __launch_bounds__(512, 2)
void k_attn(const float* __restrict__ value, const float* __restrict__ tc_,
            const float* __restrict__ fc_, const float* __restrict__ qtilde,
            const float* __restrict__ qb, float* __restrict__ tsum_out) {
    const int r    = blockIdx.x;       // 0..1023
    const int b    = r >> 9;
    const int t    = threadIdx.x;
    const int w    = t >> 6;           // wave 0..7
    const int lane = t & 63;

    __shared__ float tsum[NH][DIM];    // 16 KB
    __shared__ float wm[8][NH], wl[8][NH], glds[NH];

    for (int i = t; i < NH * DIM; i += 512) ((float*)tsum)[i] = 0.f;

    const float tc = tc_[r], fc = fc_[r];
    const int lid  = w >> 1;
    const int Wl   = 1024 >> lid;
    const int Hl   = 64 >> lid;
    const int lsi  = (lid == 0) ? 0 : (lid == 1) ? 65536 : (lid == 2) ? 81920 : 86016;
    const int tcpx = (int)rintf(tc * (float)Wl - 0.5f);
    const int fcpx = (int)rintf(fc * (float)Hl - 0.5f);

    // q-tilde fragment for this lane's 8 dims, all 8 heads (registers)
    float qt[NH][8];
    const float* qtp = qtilde + (size_t)r * (NH * DIM) + lane * 8;
    #pragma unroll
    for (int h = 0; h < NH; ++h) {
        const float4 a = *(const float4*)(qtp + h * DIM);
        const float4 c = *(const float4*)(qtp + h * DIM + 4);
        qt[h][0] = a.x; qt[h][1] = a.y; qt[h][2] = a.z; qt[h][3] = a.w;
        qt[h][4] = c.x; qt[h][5] = c.y; qt[h][6] = c.z; qt[h][7] = c.w;
    }
    float qbv[NH];
    #pragma unroll
    for (int h = 0; h < NH; ++h) qbv[h] = qb[r * NH + h];

    float m[NH], l[NH], acc[NH][8];
    #pragma unroll
    for (int h = 0; h < NH; ++h) {
        m[h] = -1e30f; l[h] = 0.f;
        #pragma unroll
        for (int j = 0; j < 8; ++j) acc[h][j] = 0.f;
    }

    const float* vbase = value + (size_t)b * NTOK * DIM;

    for (int i = 0; i < 64; ++i) {
        const int local = (w & 1) * 64 + i;
        const int fi = local >> 4, ti = local & 15;
        const int tt = tcpx + ti - 8;
        const int ff = fcpx + fi - 4;
        const bool oob = (tt < 0) | (tt >= Wl) | (ff < 0) | (ff >= Hl);
        const int tcl = min(max(tt, 0), Wl - 1);
        const int fcl = min(max(ff, 0), Hl - 1);
        const int rowidx = lsi + fcl * Wl + tcl;

        float tok[8];
        if (!oob) {
            const float* src = vbase + (size_t)rowidx * DIM + lane * 8;
            const float4 a = *(const float4*)src;
            const float4 c = *(const float4*)(src + 4);
            tok[0] = a.x; tok[1] = a.y; tok[2] = a.z; tok[3] = a.w;
            tok[4] = c.x; tok[5] = c.y; tok[6] = c.z; tok[7] = c.w;
        } else {
            #pragma unroll
            for (int j = 0; j < 8; ++j) tok[j] = 0.f;
        }

        float s[NH];
        #pragma unroll
        for (int h = 0; h < NH; ++h) {
            float a = 0.f;
            #pragma unroll
            for (int j = 0; j < 8; ++j) a = fmaf(qt[h][j], tok[j], a);
            s[h] = a;
        }
        // cross-lane butterfly reduce (all 8 heads)
        #pragma unroll
        for (int off = 1; off < 64; off <<= 1) {
            #pragma unroll
            for (int h = 0; h < NH; ++h) s[h] += __shfl_xor(s[h], off);
        }
        #pragma unroll
        for (int h = 0; h < NH; ++h) s[h] = (s[h] + qbv[h]) * 0.125f;

        // online softmax update (s,m wave-uniform -> uniform branch)
        #pragma unroll
        for (int h = 0; h < NH; ++h) {
            if (s[h] > m[h]) {
                const float corr = __expf(m[h] - s[h]);
                l[h] *= corr;
                #pragma unroll
                for (int j = 0; j < 8; ++j) acc[h][j] *= corr;
                m[h] = s[h];
            }
            const float p = __expf(s[h] - m[h]);
            l[h] += p;
            #pragma unroll
            for (int j = 0; j < 8; ++j) acc[h][j] = fmaf(p, tok[j], acc[h][j]);
        }
    }

    // ---- cross-wave merge ----
    if (lane == 0) {
        #pragma unroll
        for (int h = 0; h < NH; ++h) { wm[w][h] = m[h]; wl[w][h] = l[h]; }
    }
    __syncthreads();

    float sc[NH];
    {
        float gm[NH], gl[NH];
        #pragma unroll
        for (int h = 0; h < NH; ++h) {
            float mm = wm[0][h];
            #pragma unroll
            for (int ww = 1; ww < 8; ++ww) mm = fmaxf(mm, wm[ww][h]);
            float ll = 0.f;
            #pragma unroll
            for (int ww = 0; ww < 8; ++ww) ll += wl[ww][h] * __expf(wm[ww][h] - mm);
            gm[h] = mm; gl[h] = ll;
            sc[h] = __expf(m[h] - mm);
        }
        if (t == 0) {
            #pragma unroll
            for (int h = 0; h < NH; ++h) glds[h] = gl[h];
        }
    }

    for (int turn = 0; turn < 8; ++turn) {
        if (w == turn) {
            #pragma unroll
            for (int h = 0; h < NH; ++h) {
                #pragma unroll
                for (int j = 0; j < 8; ++j)
                    tsum[h][lane * 8 + j] += sc[h] * acc[h][j];
            }
        }
        __syncthreads();
    }

    // write tsum / L  (thread t owns elems [t*8, t*8+8), all same head t>>6)
    float* dst = tsum_out + (size_t)r * (NH * DIM);
    const float inv = 1.f / glds[t >> 6];
    #pragma unroll
    for (int i = 0; i < 8; ++i)
        dst[t * 8 + i] = ((const float*)tsum)[t * 8 + i] * inv;
}

// ---------------------------------------------------------------------------
// Kernel 4: out = (concat_h tsum_h @ Wv_h + bv) @ Wo + bo   (2 rows / block)
// ---------------------------------------------------------------------------
__global__ __launch_bounds__(256)
void k_out(const float* __restrict__ tsum, const float* __restrict__ Wv,
           const float* __restrict__ bv, const float* __restrict__ Wo,
           const float* __restrict__ bo, float* __restrict__ out) {
    __shared__ float ts[2][NH * DIM];  // 32 KB
    __shared__ float o1[2][DIM];       // 4 KB
    const int r0 = blockIdx.x * 2;
    const int t  = threadIdx.x;
    for (int i = t; i < 2 * NH * DIM; i += 256)
        ((float*)ts)[i] = tsum[(size_t)r0 * (NH * DIM) + i];
    __syncthreads();
    for (int rep = 0; rep < 2; ++rep) {
        const int c = t + rep * 256;
        const int h = c >> 6;
        float a0 = bv[c], a1 = bv[c];
        for (int d = 0; d < DIM; ++d) {
            const float wv = Wv[d * DIM + c];
            a0 = fmaf(ts[0][h * DIM + d], wv, a0);
            a1 = fmaf(ts[1][h * DIM + d], wv, a1);
        }
        o1[0][c] = a0; o1[1][c] = a1;
    }
    __syncthreads();
    for (int rep = 0; rep < 2; ++rep) {
        const int c = t + rep * 256;
        float a0 = bo[c], a1 = bo[c];
        for (int d = 0; d < DIM; ++d) {
            const float wo = Wo[d * DIM + c];
            a0 = fmaf(o1[0][d], wo, a0);
            a1 = fmaf(o1[1][d], wo, a1);
        }
        out[(size_t)r0 * DIM + c]       = a0;
        out[(size_t)(r0 + 1) * DIM + c] = a1;
    }
}

// ---------------------------------------------------------------------------
extern "C" void kernel_launch(void* const* d_in, const int* in_sizes, int n_in,
                              void* d_out, int out_size, void* d_ws, size_t ws_size,
                              hipStream_t stream) {
    const float* query = (const float*)d_in[0];
    const float* tc    = (const float*)d_in[1];
    const float* fc    = (const float*)d_in[2];
    const float* value = (const float*)d_in[3];
    const float* Wq    = (const float*)d_in[4];
    const float* bq    = (const float*)d_in[5];
    const float* Wk    = (const float*)d_in[6];
    const float* bk    = (const float*)d_in[7];
    const float* Wv    = (const float*)d_in[8];
    const float* bv    = (const float*)d_in[9];
    const float* Wo    = (const float*)d_in[10];
    const float* bo    = (const float*)d_in[11];
    float* out = (float*)d_out;

    char* ws = (char*)d_ws;
    float* Q  = (float*)(ws);                     // 1024*512   f32 =  2 MB
    float* QT = (float*)(ws + (size_t)(2  << 20)); // 1024*8*512 f32 = 16 MB
    float* QB = (float*)(ws + (size_t)(18 << 20)); // 1024*8     f32 = 32 KB
    float* TS = (float*)(ws + (size_t)(19 << 20)); // 1024*8*512 f32 = 16 MB

    hipLaunchKernelGGL(k_qproj,  dim3(256),  dim3(256), 0, stream, query, Wq, bq, Q);
    hipLaunchKernelGGL(k_qtilde, dim3(256),  dim3(256), 0, stream, Q, Wk, bk, QT, QB);
    hipLaunchKernelGGL(k_attn,   dim3(1024), dim3(512), 0, stream, value, tc, fc, QT, QB, TS);
    hipLaunchKernelGGL(k_out,    dim3(512),  dim3(256), 0, stream, TS, Wv, bv, Wo, bo, out);
}